// Round 1
// baseline (3332.776 us; speedup 1.0000x reference)
//
#include <hip/hip_runtime.h>
#include <hip/hip_bf16.h>

// Problem constants
#define BB   4096
#define TT   128
#define OBS  64
#define ACT  16
#define DD   64
#define HH   256
#define G4   1024   // 4*H
#define BD   262144 // B*D

typedef short bshort8 __attribute__((ext_vector_type(8)));
typedef float f32x4  __attribute__((ext_vector_type(4)));

__device__ __forceinline__ unsigned short f2bf(float f) {
    union { float f; unsigned int u; } v; v.f = f;
    unsigned int u = v.u;
    u += 0x7FFFu + ((u >> 16) & 1u);   // RNE
    return (unsigned short)(u >> 16);
}
__device__ __forceinline__ float bf2f(unsigned short s) {
    union { unsigned int u; float f; } v; v.u = ((unsigned int)s) << 16;
    return v.f;
}

// ---------------- pack weights: Wt[ko][col][j] = B[8*ko+j][col], bf16 -------
// B = [Wx (64 rows) ; Wh (256 rows)] -> K = 320 = 40 k-octs, 1024 cols
__global__ void pack_wt(const float* __restrict__ Wx, const float* __restrict__ Wh,
                        unsigned short* __restrict__ wt) {
    int idx = blockIdx.x * 256 + threadIdx.x;      // < 40*1024*8 = 327680
    int j   = idx & 7;
    int col = (idx >> 3) & 1023;
    int ko  = idx >> 13;
    int k   = ko * 8 + j;
    float v = (k < 64) ? Wx[k * 1024 + col] : Wh[(k - 64) * 1024 + col];
    wt[idx] = f2bf(v);
}

// ---------------- embed: x_pre = feats@We + be ; write bf16 + partial stats --
__global__ void embed_kernel(const float* __restrict__ obs, const float* __restrict__ act,
                             const float* __restrict__ We,  const float* __restrict__ be,
                             unsigned short* __restrict__ x,
                             float* __restrict__ p1, float* __restrict__ p2) {
    int chunk = blockIdx.x;   // 0..63  (64 rows each)
    int t     = blockIdx.y;   // 0..127
    __shared__ __align__(16) float Wl[80 * 64];
    __shared__ float red1[16][64];
    __shared__ float red2[16][64];
    int tid = threadIdx.x;
    for (int i = tid; i < 80 * 64; i += 256) Wl[i] = We[i];
    __syncthreads();

    int dg  = tid & 15;   // d-group: d = 4*dg .. +3
    int rg2 = tid >> 4;   // 0..15 row sub-group
    int d0  = dg * 4;
    float s1[4] = {0, 0, 0, 0}, s2[4] = {0, 0, 0, 0};
    float be0 = be[d0], be1 = be[d0 + 1], be2 = be[d0 + 2], be3 = be[d0 + 3];

    for (int i = 0; i < 4; ++i) {
        int b = chunk * 64 + i * 16 + rg2;
        const float* orow = obs + ((size_t)b * TT + t) * OBS;
        const float* arow = act + ((size_t)b * TT + t) * ACT;
        float a0 = be0, a1 = be1, a2 = be2, a3 = be3;
        for (int f = 0; f < 64; ++f) {
            float fv = orow[f];
            float4 w = *reinterpret_cast<const float4*>(&Wl[f * 64 + d0]);
            a0 += fv * w.x; a1 += fv * w.y; a2 += fv * w.z; a3 += fv * w.w;
        }
        for (int f = 0; f < 16; ++f) {
            float fv = arow[f];
            float4 w = *reinterpret_cast<const float4*>(&Wl[(64 + f) * 64 + d0]);
            a0 += fv * w.x; a1 += fv * w.y; a2 += fv * w.z; a3 += fv * w.w;
        }
        s1[0] += a0; s2[0] += a0 * a0;
        s1[1] += a1; s2[1] += a1 * a1;
        s1[2] += a2; s2[2] += a2 * a2;
        s1[3] += a3; s2[3] += a3 * a3;
        unsigned int lo = (unsigned)f2bf(a0) | ((unsigned)f2bf(a1) << 16);
        unsigned int hi = (unsigned)f2bf(a2) | ((unsigned)f2bf(a3) << 16);
        *reinterpret_cast<uint2*>(x + ((size_t)t * BB + b) * DD + d0) = make_uint2(lo, hi);
    }
    for (int q = 0; q < 4; ++q) { red1[rg2][d0 + q] = s1[q]; red2[rg2][d0 + q] = s2[q]; }
    __syncthreads();
    if (tid < 64) {
        float a = 0.f, b2 = 0.f;
        for (int g2 = 0; g2 < 16; ++g2) { a += red1[g2][tid]; b2 += red2[g2][tid]; }
        size_t o = ((size_t)t * 64 + chunk) * 64 + tid;
        p1[o] = a; p2[o] = b2;
    }
}

// ---------------- BN stats finalize: a = rstd*scale, bb = bias - m*a ---------
__global__ void bn_stats(const float* __restrict__ p1, const float* __restrict__ p2,
                         const float* __restrict__ scale, const float* __restrict__ bias,
                         float* __restrict__ sa, float* __restrict__ sb) {
    int t = blockIdx.x, d = threadIdx.x;  // 64 threads
    float s1 = 0.f, s2 = 0.f;
    for (int c = 0; c < 64; ++c) {
        size_t o = ((size_t)t * 64 + c) * 64 + d;
        s1 += p1[o]; s2 += p2[o];
    }
    float m   = s1 * (1.0f / 4096.0f);
    float var = s2 * (1.0f / 4096.0f) - m * m;
    float a   = rsqrtf(var + 1e-5f) * scale[d];
    sa[t * 64 + d] = a;
    sb[t * 64 + d] = bias[d] - m * a;
}

// ---------------- BN apply + leaky ReLU (in-place on bf16 x) ----------------
__global__ void bn_apply(unsigned short* __restrict__ x,
                         const float* __restrict__ sa, const float* __restrict__ sb) {
    size_t e8 = (size_t)blockIdx.x * 256 + threadIdx.x;  // < T*B*8
    int d8  = (int)(e8 & 7);
    size_t row = e8 >> 3;            // t*B + b
    int t   = (int)(row >> 12);
    int d0  = d8 * 8;
    unsigned short* px = x + row * DD + d0;
    uint4 v = *reinterpret_cast<uint4*>(px);
    unsigned short* u = reinterpret_cast<unsigned short*>(&v);
    const float* a  = sa + t * 64 + d0;
    const float* bb = sb + t * 64 + d0;
#pragma unroll
    for (int q = 0; q < 8; ++q) {
        float xv = bf2f(u[q]);
        float y  = a[q] * xv + bb[q];
        y = (y >= 0.f) ? y : 0.2f * y;
        u[q] = f2bf(y);
    }
    *reinterpret_cast<uint4*>(px) = v;
}

// ---------------- LSTM step: z = [x_t|h]@[Wx;Wh], gates, update c/h ---------
// grid (64 row-groups, 4 hidden-groups), 256 threads (4 waves)
__global__ void __launch_bounds__(256)
lstm_step(const unsigned short* __restrict__ x, const unsigned short* __restrict__ wt,
          const unsigned short* __restrict__ h_prev, unsigned short* __restrict__ h_next,
          float* __restrict__ c_glob, const float* __restrict__ b_lstm, int t) {
    __shared__ __align__(16) unsigned short A[64 * 328];  // [row][40 ko * 8 + pad]
    int rg = blockIdx.x, cg = blockIdx.y;
    int tid = threadIdx.x;

    { // stage x_t rows (k = 0..63)
        const unsigned short* xs = x + ((size_t)t * BB + rg * 64) * DD;
        for (int idx = tid; idx < 512; idx += 256) {
            int row = idx >> 3, ko = idx & 7;
            *reinterpret_cast<uint4*>(&A[row * 328 + ko * 8]) =
                *reinterpret_cast<const uint4*>(xs + row * DD + ko * 8);
        }
        // stage h rows (k = 64..319)
        const unsigned short* hs = h_prev + (size_t)rg * 64 * HH;
        for (int idx = tid; idx < 2048; idx += 256) {
            int row = idx >> 5, kk = idx & 31;
            *reinterpret_cast<uint4*>(&A[row * 328 + 64 + kk * 8]) =
                *reinterpret_cast<const uint4*>(hs + row * HH + kk * 8);
        }
    }
    __syncthreads();

    int lane = tid & 63, w = tid >> 6;
    int l15 = lane & 15, lhi = lane >> 4;
    int u = cg * 64 + w * 16 + l15;   // hidden index 0..255

    f32x4 acc[4][4];
#pragma unroll
    for (int rf = 0; rf < 4; ++rf)
#pragma unroll
        for (int g = 0; g < 4; ++g) acc[rf][g] = (f32x4)0.f;

#pragma unroll
    for (int ko2 = 0; ko2 < 10; ++ko2) {
        int ko = ko2 * 4 + lhi;
        bshort8 a[4], bfr[4];
#pragma unroll
        for (int rf = 0; rf < 4; ++rf)
            a[rf] = *reinterpret_cast<const bshort8*>(&A[(rf * 16 + l15) * 328 + ko * 8]);
#pragma unroll
        for (int g = 0; g < 4; ++g)
            bfr[g] = *reinterpret_cast<const bshort8*>(wt + ((size_t)ko * 1024 + g * 256 + u) * 8);
#pragma unroll
        for (int rf = 0; rf < 4; ++rf)
#pragma unroll
            for (int g = 0; g < 4; ++g)
                acc[rf][g] = __builtin_amdgcn_mfma_f32_16x16x32_bf16(a[rf], bfr[g], acc[rf][g], 0, 0, 0);
    }

    float bl0 = b_lstm[u], bl1 = b_lstm[256 + u], bl2 = b_lstm[512 + u], bl3 = b_lstm[768 + u];
#pragma unroll
    for (int rf = 0; rf < 4; ++rf) {
#pragma unroll
        for (int r = 0; r < 4; ++r) {
            int brow = rg * 64 + rf * 16 + lhi * 4 + r;
            size_t ci = (size_t)brow * HH + u;
            float zi = acc[rf][0][r] + bl0;
            float zf = acc[rf][1][r] + bl1;
            float zg = acc[rf][2][r] + bl2;
            float zo = acc[rf][3][r] + bl3;
            float si = 1.f / (1.f + __expf(-zi));
            float sf = 1.f / (1.f + __expf(-zf));
            float so = 1.f / (1.f + __expf(-zo));
            float tg = 2.f / (1.f + __expf(-2.f * zg)) - 1.f;
            float cn = sf * c_glob[ci] + si * tg;
            float tc = 2.f / (1.f + __expf(-2.f * cn)) - 1.f;
            c_glob[ci] = cn;
            h_next[ci] = f2bf(so * tc);
        }
    }
}

// ---------------- heads: mu = h@Wmu + bmu ; log_std clipped ------------------
__global__ void heads(const unsigned short* __restrict__ h,
                      const float* __restrict__ Wmu, const float* __restrict__ bmu,
                      const float* __restrict__ Wls, const float* __restrict__ bls,
                      float* __restrict__ out) {
    int tid = threadIdx.x;
    int b = blockIdx.x * 4 + (tid >> 6);
    int d = tid & 63;
    const unsigned short* hr = h + (size_t)b * HH;
    float mu = 0.f, ls = 0.f;
    for (int k = 0; k < HH; ++k) {
        float hv = bf2f(hr[k]);
        mu += hv * Wmu[k * 64 + d];
        ls += hv * Wls[k * 64 + d];
    }
    mu += bmu[d];
    ls += bls[d];
    ls = fminf(fmaxf(ls, -10.f), 2.f);
    out[(size_t)b * 64 + d] = mu;
    out[BD + (size_t)b * 64 + d] = ls;
}

extern "C" void kernel_launch(void* const* d_in, const int* in_sizes, int n_in,
                              void* d_out, int out_size, void* d_ws, size_t ws_size,
                              hipStream_t stream) {
    const float* obs = (const float*)d_in[0];
    const float* act = (const float*)d_in[1];
    const float* We  = (const float*)d_in[2];
    const float* be  = (const float*)d_in[3];
    const float* bns = (const float*)d_in[4];
    const float* bnb = (const float*)d_in[5];
    const float* Wx  = (const float*)d_in[6];
    const float* Wh  = (const float*)d_in[7];
    const float* bl  = (const float*)d_in[8];
    const float* Wmu = (const float*)d_in[9];
    const float* bmu = (const float*)d_in[10];
    const float* Wls = (const float*)d_in[11];
    const float* bls = (const float*)d_in[12];

    char* ws = (char*)d_ws;
    // workspace layout (all 256B aligned by construction)
    unsigned short* xbf = (unsigned short*)(ws + 0);            // 128*4096*64 bf16 = 64MB
    unsigned short* wt  = (unsigned short*)(ws + 67108864);     // 40*1024*8 bf16 = 640KB
    unsigned short* h0  = (unsigned short*)(ws + 67764224);     // 4096*256 bf16 = 2MB
    unsigned short* h1  = (unsigned short*)(ws + 69861376);     // 2MB
    float* cbuf         = (float*)(ws + 71958528);              // 4096*256 f32 = 4MB
    float* p1           = (float*)(ws + 76152832);              // 128*64*64 f32 = 2MB
    float* p2           = (float*)(ws + 78249984);              // 2MB
    float* sa           = (float*)(ws + 80347136);              // 128*64 f32
    float* sb           = (float*)(ws + 80379904);

    hipMemsetAsync(h0, 0, (size_t)BB * HH * 2, stream);
    hipMemsetAsync(cbuf, 0, (size_t)BB * HH * 4, stream);

    pack_wt<<<1280, 256, 0, stream>>>(Wx, Wh, wt);
    embed_kernel<<<dim3(64, 128), 256, 0, stream>>>(obs, act, We, be, xbf, p1, p2);
    bn_stats<<<128, 64, 0, stream>>>(p1, p2, bns, bnb, sa, sb);
    bn_apply<<<16384, 256, 0, stream>>>(xbf, sa, sb);

    for (int t = 0; t < TT; ++t) {
        const unsigned short* hp = (t & 1) ? h1 : h0;
        unsigned short*       hn = (t & 1) ? h0 : h1;
        lstm_step<<<dim3(64, 4), 256, 0, stream>>>(xbf, wt, hp, hn, cbuf, bl, t);
    }

    heads<<<1024, 256, 0, stream>>>(h0, Wmu, bmu, Wls, bls, (float*)d_out);
}

// Round 2
// 1601.771 us; speedup vs baseline: 2.0807x; 2.0807x over previous
//
#include <hip/hip_runtime.h>
#include <hip/hip_bf16.h>

// Problem constants
#define BB   4096
#define TT   128
#define OBS  64
#define ACT  16
#define DD   64
#define HH   256
#define G4   1024   // 4*H
#define BD   262144 // B*D

typedef short bshort8 __attribute__((ext_vector_type(8)));
typedef float f32x4  __attribute__((ext_vector_type(4)));

__device__ __forceinline__ unsigned short f2bf(float f) {
    union { float f; unsigned int u; } v; v.f = f;
    unsigned int u = v.u;
    u += 0x7FFFu + ((u >> 16) & 1u);   // RNE
    return (unsigned short)(u >> 16);
}
__device__ __forceinline__ float bf2f(unsigned short s) {
    union { unsigned int u; float f; } v; v.u = ((unsigned int)s) << 16;
    return v.f;
}

// ---------------- pack weights: Wt[ko][col][j] = B[8*ko+j][col], bf16 -------
// B = [Wx (64 rows) ; Wh (256 rows)] -> K = 320 = 40 k-octs, 1024 cols
__global__ void pack_wt(const float* __restrict__ Wx, const float* __restrict__ Wh,
                        unsigned short* __restrict__ wt) {
    int idx = blockIdx.x * 256 + threadIdx.x;      // < 40*1024*8 = 327680
    int j   = idx & 7;
    int col = (idx >> 3) & 1023;
    int ko  = idx >> 13;
    int k   = ko * 8 + j;
    float v = (k < 64) ? Wx[k * 1024 + col] : Wh[(k - 64) * 1024 + col];
    wt[idx] = f2bf(v);
}

// ---------------- embed: one block per batch row b, all 128 timesteps -------
// A tile [128 t][80 k] staged coalesced in LDS (stride 84), W [80][64] in LDS.
// Thread (rg=tid&15, cg=tid>>4) computes rows r=rg+16i (i<8), cols c0=cg*4..+3.
__global__ void __launch_bounds__(256)
embed_tiled(const float* __restrict__ obs, const float* __restrict__ act,
            const float* __restrict__ We,  const float* __restrict__ be,
            unsigned short* __restrict__ x) {
    int b   = blockIdx.x;
    int tid = threadIdx.x;
    __shared__ __align__(16) float A[128 * 84];
    __shared__ __align__(16) float W[80 * 64];

    // stage W: 5120 floats = 1280 float4, coalesced
    for (int i = tid; i < 1280; i += 256)
        *reinterpret_cast<f32x4*>(&W[i * 4]) = *reinterpret_cast<const f32x4*>(&We[i * 4]);
    // stage obs: 128*64 floats = 2048 float4, contiguous 32KB, coalesced
    const float* ob = obs + (size_t)b * (TT * OBS);
#pragma unroll
    for (int it = 0; it < 8; ++it) {
        int i4 = tid + it * 256;
        f32x4 v = *reinterpret_cast<const f32x4*>(ob + i4 * 4);
        int e = i4 * 4, t = e >> 6, f = e & 63;
        *reinterpret_cast<f32x4*>(&A[t * 84 + f]) = v;
    }
    // stage act: 128*16 floats = 512 float4, contiguous 8KB
    const float* ar = act + (size_t)b * (TT * ACT);
#pragma unroll
    for (int it = 0; it < 2; ++it) {
        int i4 = tid + it * 256;
        f32x4 v = *reinterpret_cast<const f32x4*>(ar + i4 * 4);
        int e = i4 * 4, t = e >> 4, f = e & 15;
        *reinterpret_cast<f32x4*>(&A[t * 84 + 64 + f]) = v;
    }
    __syncthreads();

    int rg = tid & 15, cg = tid >> 4;
    int c0 = cg * 4;
    float acc[8][4];
    float be0 = be[c0], be1 = be[c0 + 1], be2 = be[c0 + 2], be3 = be[c0 + 3];
#pragma unroll
    for (int i = 0; i < 8; ++i) {
        acc[i][0] = be0; acc[i][1] = be1; acc[i][2] = be2; acc[i][3] = be3;
    }

    for (int kq = 0; kq < 20; ++kq) {
        f32x4 A4[8];
#pragma unroll
        for (int i = 0; i < 8; ++i)
            A4[i] = *reinterpret_cast<const f32x4*>(&A[(rg + 16 * i) * 84 + kq * 4]);
        f32x4 W0 = *reinterpret_cast<const f32x4*>(&W[(kq * 4 + 0) * 64 + c0]);
        f32x4 W1 = *reinterpret_cast<const f32x4*>(&W[(kq * 4 + 1) * 64 + c0]);
        f32x4 W2 = *reinterpret_cast<const f32x4*>(&W[(kq * 4 + 2) * 64 + c0]);
        f32x4 W3 = *reinterpret_cast<const f32x4*>(&W[(kq * 4 + 3) * 64 + c0]);
#pragma unroll
        for (int i = 0; i < 8; ++i) {
#pragma unroll
            for (int j = 0; j < 4; ++j) {
                acc[i][j] += A4[i][0] * W0[j] + A4[i][1] * W1[j]
                           + A4[i][2] * W2[j] + A4[i][3] * W3[j];
            }
        }
    }

#pragma unroll
    for (int i = 0; i < 8; ++i) {
        int t = rg + 16 * i;
        unsigned int lo = (unsigned)f2bf(acc[i][0]) | ((unsigned)f2bf(acc[i][1]) << 16);
        unsigned int hi = (unsigned)f2bf(acc[i][2]) | ((unsigned)f2bf(acc[i][3]) << 16);
        *reinterpret_cast<uint2*>(x + ((size_t)t * BB + b) * DD + c0) = make_uint2(lo, hi);
    }
}

// ---------------- BN partial stats from bf16 x: p[t][slice][64] -------------
__global__ void stats_x(const unsigned short* __restrict__ x,
                        float* __restrict__ p1, float* __restrict__ p2) {
    int t = blockIdx.x, s = blockIdx.y;
    int tid = threadIdx.x;
    int dg = tid & 15, bl = tid >> 4;
    int d0 = dg * 4;
    float s1[4] = {0, 0, 0, 0}, s2[4] = {0, 0, 0, 0};
    const unsigned short* xt = x + (size_t)t * BB * DD;
    for (int it = 0; it < 32; ++it) {
        int b = s * 512 + it * 16 + bl;
        uint2 v = *reinterpret_cast<const uint2*>(xt + (size_t)b * DD + d0);
        const unsigned short* u = reinterpret_cast<const unsigned short*>(&v);
#pragma unroll
        for (int q = 0; q < 4; ++q) {
            float xv = bf2f(u[q]);
            s1[q] += xv; s2[q] += xv * xv;
        }
    }
    __shared__ float r1[16][64];
    __shared__ float r2[16][64];
#pragma unroll
    for (int q = 0; q < 4; ++q) { r1[bl][d0 + q] = s1[q]; r2[bl][d0 + q] = s2[q]; }
    __syncthreads();
    if (tid < 64) {
        float a = 0.f, b2 = 0.f;
        for (int g = 0; g < 16; ++g) { a += r1[g][tid]; b2 += r2[g][tid]; }
        size_t o = ((size_t)t * 8 + s) * 64 + tid;
        p1[o] = a; p2[o] = b2;
    }
}

// ---------------- BN stats finalize: a = rstd*scale, bb = bias - m*a ---------
__global__ void bn_stats(const float* __restrict__ p1, const float* __restrict__ p2,
                         const float* __restrict__ scale, const float* __restrict__ bias,
                         float* __restrict__ sa, float* __restrict__ sb) {
    int t = blockIdx.x, d = threadIdx.x;  // 64 threads
    float s1 = 0.f, s2 = 0.f;
    for (int c = 0; c < 8; ++c) {
        size_t o = ((size_t)t * 8 + c) * 64 + d;
        s1 += p1[o]; s2 += p2[o];
    }
    float m   = s1 * (1.0f / 4096.0f);
    float var = s2 * (1.0f / 4096.0f) - m * m;
    float a   = rsqrtf(var + 1e-5f) * scale[d];
    sa[t * 64 + d] = a;
    sb[t * 64 + d] = bias[d] - m * a;
}

// ---------------- BN apply + leaky ReLU (in-place on bf16 x) ----------------
__global__ void bn_apply(unsigned short* __restrict__ x,
                         const float* __restrict__ sa, const float* __restrict__ sb) {
    size_t e8 = (size_t)blockIdx.x * 256 + threadIdx.x;  // < T*B*8
    int d8  = (int)(e8 & 7);
    size_t row = e8 >> 3;            // t*B + b
    int t   = (int)(row >> 12);
    int d0  = d8 * 8;
    unsigned short* px = x + row * DD + d0;
    uint4 v = *reinterpret_cast<uint4*>(px);
    unsigned short* u = reinterpret_cast<unsigned short*>(&v);
    const float* a  = sa + t * 64 + d0;
    const float* bb = sb + t * 64 + d0;
#pragma unroll
    for (int q = 0; q < 8; ++q) {
        float xv = bf2f(u[q]);
        float y  = a[q] * xv + bb[q];
        y = (y >= 0.f) ? y : 0.2f * y;
        u[q] = f2bf(y);
    }
    *reinterpret_cast<uint4*>(px) = v;
}

// ---------------- LSTM step: z = [x_t|h]@[Wx;Wh], gates, update c/h ---------
// grid (64 row-groups, 4 hidden-groups), 256 threads (4 waves)
__global__ void __launch_bounds__(256)
lstm_step(const unsigned short* __restrict__ x, const unsigned short* __restrict__ wt,
          const unsigned short* __restrict__ h_prev, unsigned short* __restrict__ h_next,
          float* __restrict__ c_glob, const float* __restrict__ b_lstm, int t) {
    __shared__ __align__(16) unsigned short A[64 * 328];  // [row][40 ko * 8 + pad]
    int rg = blockIdx.x, cg = blockIdx.y;
    int tid = threadIdx.x;

    { // stage x_t rows (k = 0..63)
        const unsigned short* xs = x + ((size_t)t * BB + rg * 64) * DD;
        for (int idx = tid; idx < 512; idx += 256) {
            int row = idx >> 3, ko = idx & 7;
            *reinterpret_cast<uint4*>(&A[row * 328 + ko * 8]) =
                *reinterpret_cast<const uint4*>(xs + row * DD + ko * 8);
        }
        // stage h rows (k = 64..319)
        const unsigned short* hs = h_prev + (size_t)rg * 64 * HH;
        for (int idx = tid; idx < 2048; idx += 256) {
            int row = idx >> 5, kk = idx & 31;
            *reinterpret_cast<uint4*>(&A[row * 328 + 64 + kk * 8]) =
                *reinterpret_cast<const uint4*>(hs + row * HH + kk * 8);
        }
    }
    __syncthreads();

    int lane = tid & 63, w = tid >> 6;
    int l15 = lane & 15, lhi = lane >> 4;
    int u = cg * 64 + w * 16 + l15;   // hidden index 0..255

    f32x4 acc[4][4];
#pragma unroll
    for (int rf = 0; rf < 4; ++rf)
#pragma unroll
        for (int g = 0; g < 4; ++g) acc[rf][g] = (f32x4)0.f;

#pragma unroll
    for (int ko2 = 0; ko2 < 10; ++ko2) {
        int ko = ko2 * 4 + lhi;
        bshort8 a[4], bfr[4];
#pragma unroll
        for (int rf = 0; rf < 4; ++rf)
            a[rf] = *reinterpret_cast<const bshort8*>(&A[(rf * 16 + l15) * 328 + ko * 8]);
#pragma unroll
        for (int g = 0; g < 4; ++g)
            bfr[g] = *reinterpret_cast<const bshort8*>(wt + ((size_t)ko * 1024 + g * 256 + u) * 8);
#pragma unroll
        for (int rf = 0; rf < 4; ++rf)
#pragma unroll
            for (int g = 0; g < 4; ++g)
                acc[rf][g] = __builtin_amdgcn_mfma_f32_16x16x32_bf16(a[rf], bfr[g], acc[rf][g], 0, 0, 0);
    }

    float bl0 = b_lstm[u], bl1 = b_lstm[256 + u], bl2 = b_lstm[512 + u], bl3 = b_lstm[768 + u];
#pragma unroll
    for (int rf = 0; rf < 4; ++rf) {
#pragma unroll
        for (int r = 0; r < 4; ++r) {
            int brow = rg * 64 + rf * 16 + lhi * 4 + r;
            size_t ci = (size_t)brow * HH + u;
            float zi = acc[rf][0][r] + bl0;
            float zf = acc[rf][1][r] + bl1;
            float zg = acc[rf][2][r] + bl2;
            float zo = acc[rf][3][r] + bl3;
            float si = 1.f / (1.f + __expf(-zi));
            float sf = 1.f / (1.f + __expf(-zf));
            float so = 1.f / (1.f + __expf(-zo));
            float tg = 2.f / (1.f + __expf(-2.f * zg)) - 1.f;
            float cn = sf * c_glob[ci] + si * tg;
            float tc = 2.f / (1.f + __expf(-2.f * cn)) - 1.f;
            c_glob[ci] = cn;
            h_next[ci] = f2bf(so * tc);
        }
    }
}

// ---------------- heads: mu = h@Wmu + bmu ; log_std clipped ------------------
__global__ void heads(const unsigned short* __restrict__ h,
                      const float* __restrict__ Wmu, const float* __restrict__ bmu,
                      const float* __restrict__ Wls, const float* __restrict__ bls,
                      float* __restrict__ out) {
    int tid = threadIdx.x;
    int b = blockIdx.x * 4 + (tid >> 6);
    int d = tid & 63;
    const unsigned short* hr = h + (size_t)b * HH;
    float mu = 0.f, ls = 0.f;
    for (int k = 0; k < HH; ++k) {
        float hv = bf2f(hr[k]);
        mu += hv * Wmu[k * 64 + d];
        ls += hv * Wls[k * 64 + d];
    }
    mu += bmu[d];
    ls += bls[d];
    ls = fminf(fmaxf(ls, -10.f), 2.f);
    out[(size_t)b * 64 + d] = mu;
    out[BD + (size_t)b * 64 + d] = ls;
}

extern "C" void kernel_launch(void* const* d_in, const int* in_sizes, int n_in,
                              void* d_out, int out_size, void* d_ws, size_t ws_size,
                              hipStream_t stream) {
    const float* obs = (const float*)d_in[0];
    const float* act = (const float*)d_in[1];
    const float* We  = (const float*)d_in[2];
    const float* be  = (const float*)d_in[3];
    const float* bns = (const float*)d_in[4];
    const float* bnb = (const float*)d_in[5];
    const float* Wx  = (const float*)d_in[6];
    const float* Wh  = (const float*)d_in[7];
    const float* bl  = (const float*)d_in[8];
    const float* Wmu = (const float*)d_in[9];
    const float* bmu = (const float*)d_in[10];
    const float* Wls = (const float*)d_in[11];
    const float* bls = (const float*)d_in[12];

    char* ws = (char*)d_ws;
    // workspace layout (all 256B aligned by construction)
    unsigned short* xbf = (unsigned short*)(ws + 0);            // 128*4096*64 bf16 = 64MB
    unsigned short* wt  = (unsigned short*)(ws + 67108864);     // 40*1024*8 bf16 = 640KB
    unsigned short* h0  = (unsigned short*)(ws + 67764224);     // 4096*256 bf16 = 2MB
    unsigned short* h1  = (unsigned short*)(ws + 69861376);     // 2MB
    float* cbuf         = (float*)(ws + 71958528);              // 4096*256 f32 = 4MB
    float* p1           = (float*)(ws + 76152832);              // 128*8*64 f32 = 256KB
    float* p2           = (float*)(ws + 78249984);              // 256KB
    float* sa           = (float*)(ws + 80347136);              // 128*64 f32
    float* sb           = (float*)(ws + 80379904);

    hipMemsetAsync(h0, 0, (size_t)BB * HH * 2, stream);
    hipMemsetAsync(cbuf, 0, (size_t)BB * HH * 4, stream);

    pack_wt<<<1280, 256, 0, stream>>>(Wx, Wh, wt);
    embed_tiled<<<4096, 256, 0, stream>>>(obs, act, We, be, xbf);
    stats_x<<<dim3(128, 8), 256, 0, stream>>>(xbf, p1, p2);
    bn_stats<<<128, 64, 0, stream>>>(p1, p2, bns, bnb, sa, sb);
    bn_apply<<<16384, 256, 0, stream>>>(xbf, sa, sb);

    for (int t = 0; t < TT; ++t) {
        const unsigned short* hp = (t & 1) ? h1 : h0;
        unsigned short*       hn = (t & 1) ? h0 : h1;
        lstm_step<<<dim3(64, 4), 256, 0, stream>>>(xbf, wt, hp, hn, cbuf, bl, t);
    }

    heads<<<1024, 256, 0, stream>>>(h0, Wmu, bmu, Wls, bls, (float*)d_out);
}